// Round 11
// baseline (856.417 us; speedup 1.0000x reference)
//
#include <hip/hip_runtime.h>
#include <hip/hip_fp16.h>
#include <math.h>

#define N_NODES 100000
#define N_EDGES 1600000
#define E_TOT   (N_EDGES + N_NODES)

// bucketed CSR build
#define NB     512          // buckets
#define NPB    196          // dst-nodes per bucket (512*196 = 100352 >= N)
#define BCAP   4096         // capacity per bucket (mean 3332, +13 sigma)
#define BIN_CH 4096         // edges per bin_k workgroup
#define NBIN_WG ((E_TOT + BIN_CH - 1) / BIN_CH)

#define PAN1 (N_NODES * 16)   // halves per h1 panel (16 cols)
#define PAN2 (N_NODES * 8)    // halves per h2 panel (8 cols)

typedef __attribute__((ext_vector_type(8))) short short8v;   // 8 bf16
typedef __attribute__((ext_vector_type(4))) float float4v;

__device__ __forceinline__ float wexp(float v) {
    v = v > 0.f ? v : 0.2f * v;
    return __expf(v);
}

__device__ __forceinline__ unsigned short f2bf(float f) {
    unsigned u = __float_as_uint(f);
    return (unsigned short)((u + 0x7FFFu + ((u >> 16) & 1u)) >> 16);
}

// ---------------------------------------------------------------------------
// xprep: x fp32 -> bf16 (row-major). 4 elems/thread.
// ---------------------------------------------------------------------------
__global__ __launch_bounds__(256) void xprep_k(
    const float* __restrict__ x, unsigned short* __restrict__ xb)
{
    int gid = blockIdx.x * 256 + threadIdx.x;     // covers N*128/4 exactly
    float4 v = ((const float4*)x)[gid];
    ushort4 o;
    o.x = f2bf(v.x); o.y = f2bf(v.y); o.z = f2bf(v.z); o.w = f2bf(v.w);
    ((ushort4*)xb)[gid] = o;
}

// ---------------------------------------------------------------------------
// w1prep: W1 -> bf16 fragment order [kstep][colfrag][lane][8].
// ---------------------------------------------------------------------------
__global__ __launch_bounds__(256) void w1prep_k(
    const float* __restrict__ W1, unsigned short* __restrict__ W1b)
{
    for (int idx = threadIdx.x; idx < 16384; idx += 256) {
        int i    = idx & 7;
        int lane = (idx >> 3) & 63;
        int f    = (idx >> 9) & 7;
        int ks   = idx >> 12;
        int k   = ks * 32 + (lane >> 4) * 8 + i;
        int col = f * 16 + (lane & 15);
        W1b[idx] = f2bf(W1[k * 128 + col]);
    }
}

// ---------------------------------------------------------------------------
// GEMM1 (MFMA bf16): h1 = x @ W1, written as 8 column PANELS h1p[f][node][16]
// (panel f = cols f*16..f*16+15; 3.2 MB each -> one per-XCD L2 in fagg1).
// Fused alpha reductions. C/D: col=lane&15, row=(lane>>4)*4+reg.
// ---------------------------------------------------------------------------
__global__ __launch_bounds__(256) void gemm1_k(
    const unsigned short* __restrict__ xb, const unsigned short* __restrict__ W1b,
    const float* __restrict__ as1, const float* __restrict__ ad1,
    __half* __restrict__ h1p, float* __restrict__ asrc, float* __restrict__ adst)
{
    const int t = threadIdx.x;
    const int w = t >> 6, L = t & 63;
    const int lr = L & 15;            // A-row / C-col within frag
    const int lg = L >> 4;            // k-group / C row-group
    const int nbase = blockIdx.x * 64 + w * 16;

    float4v acc[8];
#pragma unroll
    for (int f = 0; f < 8; ++f) acc[f] = (float4v)0.f;

    int arow = nbase + lr; if (arow >= N_NODES) arow = N_NODES - 1;
    const unsigned short* xrow = xb + (size_t)arow * 128 + lg * 8;

#pragma unroll
    for (int ks = 0; ks < 4; ++ks) {
        short8v a = *(const short8v*)(xrow + ks * 32);
        const unsigned short* wb = W1b + ((size_t)ks * 8 * 64 + L) * 8;
#pragma unroll
        for (int f = 0; f < 8; ++f) {
            short8v b = *(const short8v*)(wb + (size_t)f * 512);
            acc[f] = __builtin_amdgcn_mfma_f32_16x16x32_bf16(a, b, acc[f], 0, 0, 0);
        }
    }

    float as_v[8], ad_v[8];
#pragma unroll
    for (int f = 0; f < 8; ++f) {
        as_v[f] = as1[f * 16 + lr];
        ad_v[f] = ad1[f * 16 + lr];
    }

#pragma unroll
    for (int r = 0; r < 4; ++r) {
        int node = nbase + lg * 4 + r;
        bool ok = node < N_NODES;
        if (ok) {
#pragma unroll
            for (int f = 0; f < 8; ++f)
                h1p[(size_t)f * PAN1 + (size_t)node * 16 + lr] = __float2half_rn(acc[f][r]);
        }
        float ps0 = 0.f, pd0 = 0.f, ps1 = 0.f, pd1 = 0.f;
#pragma unroll
        for (int f = 0; f < 4; ++f) { ps0 += acc[f][r] * as_v[f]; pd0 += acc[f][r] * ad_v[f]; }
#pragma unroll
        for (int f = 4; f < 8; ++f) { ps1 += acc[f][r] * as_v[f]; pd1 += acc[f][r] * ad_v[f]; }
#pragma unroll
        for (int off = 1; off < 16; off <<= 1) {
            ps0 += __shfl_xor(ps0, off); pd0 += __shfl_xor(pd0, off);
            ps1 += __shfl_xor(ps1, off); pd1 += __shfl_xor(pd1, off);
        }
        if (lr == 0 && ok) {
            asrc[node * 2 + 0] = ps0; asrc[node * 2 + 1] = ps1;
            adst[node * 2 + 0] = pd0; adst[node * 2 + 1] = pd1;
        }
    }
}

// ---------------------------------------------------------------------------
// CSR build, phase 1: bin edges by dst bucket. Edges read ONCE into regs.
// ---------------------------------------------------------------------------
__global__ __launch_bounds__(256) void bin_k(
    const int* __restrict__ ei, int* __restrict__ bcur, unsigned* __restrict__ bdata)
{
    __shared__ int hist[NB];
    __shared__ int base[NB];
    const int t = threadIdx.x;
    const int e0 = blockIdx.x * BIN_CH;

    int rs[16], rd[16];
#pragma unroll
    for (int p = 0; p < 16; ++p) {
        int e = e0 + p * 256 + t;
        if (e < E_TOT) {
            if (e < N_EDGES) { rs[p] = ei[e]; rd[p] = ei[N_EDGES + e]; }
            else             { rs[p] = rd[p] = e - N_EDGES; }
        } else rd[p] = -1;
    }

    for (int b = t; b < NB; b += 256) hist[b] = 0;
    __syncthreads();

#pragma unroll
    for (int p = 0; p < 16; ++p)
        if (rd[p] >= 0) atomicAdd(&hist[rd[p] / NPB], 1);
    __syncthreads();

    for (int b = t; b < NB; b += 256) {
        int c = hist[b];
        base[b] = c ? atomicAdd(&bcur[b], c) : 0;
        hist[b] = 0;      // reuse as local cursor
    }
    __syncthreads();

#pragma unroll
    for (int p = 0; p < 16; ++p) {
        if (rd[p] < 0) continue;
        int b  = rd[p] / NPB;
        int dl = rd[p] - b * NPB;
        int pos = base[b] + atomicAdd(&hist[b], 1);
        if (pos < BCAP)
            bdata[(size_t)b * BCAP + pos] = (unsigned)rs[p] | ((unsigned)dl << 17);
    }
}

// ---------------------------------------------------------------------------
// CSR build, phase 2a: exclusive scan of bucket counts (1 wg x 512 threads).
// ---------------------------------------------------------------------------
__global__ __launch_bounds__(512) void scanb_k(
    const int* __restrict__ bcur, int* __restrict__ bbase)
{
    __shared__ int a[NB], b_[NB];
    int t = threadIdx.x;
    int v = bcur[t];
    a[t] = v;
    __syncthreads();
    int* src = a; int* dst = b_;
    for (int off = 1; off < NB; off <<= 1) {
        dst[t] = (t >= off) ? src[t - off] + src[t] : src[t];
        __syncthreads();
        int* tmp = src; src = dst; dst = tmp;
    }
    bbase[t] = src[t] - v;   // exclusive
}

// ---------------------------------------------------------------------------
// CSR build, phase 2b: wg per bucket -> row_start + csr_src (contiguous).
// Zero-pads 16 ints past csr_src[E_TOT] (sliced fagg reads up to e+7).
// ---------------------------------------------------------------------------
__global__ __launch_bounds__(256) void build_k(
    const unsigned* __restrict__ bdata, const int* __restrict__ bcur,
    const int* __restrict__ bbase, int* __restrict__ row_start,
    int* __restrict__ csr_src)
{
    __shared__ unsigned rec[BCAP];     // 16 KB
    __shared__ int hist[256];
    __shared__ int excl[NPB];
    __shared__ int lcur[NPB];
    const int t = threadIdx.x;
    const int b = blockIdx.x;
    const int cnt = min(bcur[b], BCAP);
    const int bb = bbase[b];

    if (b == 0 && t < 16) csr_src[E_TOT + t] = 0;

    hist[t] = 0;
    if (t < NPB) lcur[t] = 0;
    __syncthreads();

    for (int i = t; i < cnt; i += 256) {
        unsigned r = bdata[(size_t)b * BCAP + i];
        rec[i] = r;
        atomicAdd(&hist[r >> 17], 1);
    }
    __syncthreads();

    int v = hist[t];
    __syncthreads();
    for (int off = 1; off < 256; off <<= 1) {
        int y = (t >= off) ? hist[t - off] : 0;
        __syncthreads();
        hist[t] += y;
        __syncthreads();
    }
    if (t < NPB) excl[t] = hist[t] - v;
    __syncthreads();

    int node = b * NPB + t;
    if (t < NPB && node <= N_NODES) row_start[node] = bb + excl[t];

    for (int i = t; i < cnt; i += 256) {
        unsigned r = rec[i];
        int dl = r >> 17;
        int s  = r & 0x1FFFF;
        int slot = atomicAdd(&lcur[dl], 1);
        csr_src[bb + excl[dl] + slot] = s;
    }
}

// ---------------------------------------------------------------------------
// Fused layer-1 aggregation, XCD-SLICED: slice = blockIdx&7 -> one 16-col
// panel (3.2 MB, fits that XCD's L2). Wave = 4 edge-slots x 16 cols.
// exp/asrc parallel across lane groups; denom via shfl; bias+ELU epilogue.
// ---------------------------------------------------------------------------
__global__ __launch_bounds__(256) void fagg1_k(
    const int* __restrict__ csr_src, const int* __restrict__ row_start,
    const float* __restrict__ asrc, const float* __restrict__ adst,
    const __half* __restrict__ h1p, const float* __restrict__ b1,
    __half* __restrict__ out1h)
{
    const int slice = blockIdx.x & 7;
    const int node = (blockIdx.x >> 3) * 4 + (threadIdx.x >> 6);
    const int L = threadIdx.x & 63;
    const int eslot = L >> 4, c16 = L & 15;
    const int col = slice * 16 + c16;
    const int h = col >> 6;                        // wave-uniform
    const int b = row_start[node], e = row_start[node + 1];
    const float ad = adst[node * 2 + h];
    const float* as_h = asrc + h;
    const __half* P = h1p + (size_t)slice * PAN1;

    float acc = 0.f, den = 0.f;
    for (int j = b; j < e; j += 4) {
        int jj = j + eslot;
        int s = csr_src[jj];                       // pad keeps in-bounds
        bool valid = jj < e;
        float w = valid ? wexp(as_h[s * 2] + ad) : 0.f;
        float x = __half2float(P[(size_t)s * 16 + c16]);
        acc += w * x; den += w;
    }

    acc += __shfl_xor(acc, 16); acc += __shfl_xor(acc, 32);
    den += __shfl_xor(den, 16); den += __shfl_xor(den, 32);

    float v = acc / (den + 1e-16f) + b1[col];
    v = v > 0.f ? v : expm1f(v);
    if (eslot == 0)
        out1h[(size_t)node * 128 + col] = __float2half_rn(v);
}

// ---------------------------------------------------------------------------
// GEMM2 (LDS-tiled): h2 = out1 @ W2, written as 8 PANELS h2p[p][node][8]
// (cols p*8..p*8+7; panels 5..7 hold the zero pad). Fused alpha2 reductions.
// ---------------------------------------------------------------------------
__global__ __launch_bounds__(256) void gemm2_k(
    const __half* __restrict__ in1h, const float* __restrict__ W2,
    const float* __restrict__ as2, const float* __restrict__ ad2,
    __half* __restrict__ h2p, float* __restrict__ asrc, float* __restrict__ adst)
{
    __shared__ float xs[64][65];      // 16.6 KB
    __shared__ float Wsh[64][64];     // 16 KB
    __shared__ float as_s[64], ad_s[64];
    const int t = threadIdx.x;
    const int nbase = blockIdx.x * 64;
    const int c4 = t & 15;
    const int ng = t >> 4;

    if (t < 64) {
        as_s[t] = (t < 40) ? as2[t] : 0.f;
        ad_s[t] = (t < 40) ? ad2[t] : 0.f;
    }

    float acc[4][4];
#pragma unroll
    for (int i = 0; i < 4; ++i)
#pragma unroll
        for (int j = 0; j < 4; ++j) acc[i][j] = 0.f;

    for (int kt = 0; kt < 128; kt += 64) {
        __syncthreads();
        {
            int r = t >> 4;
            int c = (t & 15) * 4;
#pragma unroll
            for (int p = 0; p < 4; ++p) {
                int row = p * 16 + r;
                int gr = nbase + row; if (gr > N_NODES - 1) gr = N_NODES - 1;
                const __half2* src = (const __half2*)(in1h + (size_t)gr * 128 + kt + c);
                float2 f01 = __half22float2(src[0]);
                float2 f23 = __half22float2(src[1]);
                xs[row][c + 0] = f01.x; xs[row][c + 1] = f01.y;
                xs[row][c + 2] = f23.x; xs[row][c + 3] = f23.y;
            }
        }
        for (int i = t; i < 4096; i += 256) {
            int k = i >> 6, c = i & 63;
            Wsh[k][c] = (c < 40) ? W2[(size_t)(kt + k) * 40 + c] : 0.f;
        }
        __syncthreads();

#pragma unroll 4
        for (int k = 0; k < 64; ++k) {
            float4 w = *(const float4*)&Wsh[k][c4 * 4];
            float x0 = xs[ng * 4 + 0][k], x1 = xs[ng * 4 + 1][k];
            float x2 = xs[ng * 4 + 2][k], x3 = xs[ng * 4 + 3][k];
            acc[0][0] += x0 * w.x; acc[0][1] += x0 * w.y; acc[0][2] += x0 * w.z; acc[0][3] += x0 * w.w;
            acc[1][0] += x1 * w.x; acc[1][1] += x1 * w.y; acc[1][2] += x1 * w.z; acc[1][3] += x1 * w.w;
            acc[2][0] += x2 * w.x; acc[2][1] += x2 * w.y; acc[2][2] += x2 * w.z; acc[2][3] += x2 * w.w;
            acc[3][0] += x3 * w.x; acc[3][1] += x3 * w.y; acc[3][2] += x3 * w.z; acc[3][3] += x3 * w.w;
        }
    }

    float4 as4 = *(const float4*)&as_s[c4 * 4];
    float4 ad4 = *(const float4*)&ad_s[c4 * 4];
#pragma unroll
    for (int i = 0; i < 4; ++i) {
        int node = nbase + ng * 4 + i;
        float av[4] = {acc[i][0], acc[i][1], acc[i][2], acc[i][3]};
        if (node < N_NODES) {
#pragma unroll
            for (int ii = 0; ii < 4; ++ii) {
                int c = c4 * 4 + ii;
                int p = c >> 3, off = c & 7;
                h2p[(size_t)p * PAN2 + (size_t)node * 8 + off] = __float2half_rn(av[ii]);
            }
        }
        float ps = av[0] * as4.x + av[1] * as4.y + av[2] * as4.z + av[3] * as4.w;
        float pd = av[0] * ad4.x + av[1] * ad4.y + av[2] * ad4.z + av[3] * ad4.w;
#pragma unroll
        for (int off = 1; off < 16; off <<= 1) {
            ps += __shfl_xor(ps, off);
            pd += __shfl_xor(pd, off);
        }
        if ((t & 15) == 0 && node < N_NODES) {
            asrc[node] = ps;
            adst[node] = pd;
        }
    }
}

// ---------------------------------------------------------------------------
// Fused layer-2 aggregation, XCD-SLICED: slice = blockIdx&7 -> one 8-col
// panel (1.6 MB). Wave = 8 edge-slots x 8 cols. Writes pre-softmax h3.
// ---------------------------------------------------------------------------
__global__ __launch_bounds__(256) void fagg2_k(
    const int* __restrict__ csr_src, const int* __restrict__ row_start,
    const float* __restrict__ asrc, const float* __restrict__ adst,
    const __half* __restrict__ h2p, float* __restrict__ h3)
{
    const int slice = blockIdx.x & 7;
    const int node = (blockIdx.x >> 3) * 4 + (threadIdx.x >> 6);
    const int L = threadIdx.x & 63;
    const int eslot = L >> 3, c8 = L & 7;
    const int col = slice * 8 + c8;
    const int b = row_start[node], e = row_start[node + 1];
    const float ad = adst[node];
    const __half* P = h2p + (size_t)slice * PAN2;

    float acc = 0.f, den = 0.f;
    for (int j = b; j < e; j += 8) {
        int jj = j + eslot;
        int s = csr_src[jj];                       // pad keeps in-bounds
        bool valid = jj < e;
        float w = valid ? wexp(asrc[s] + ad) : 0.f;
        float x = __half2float(P[(size_t)s * 8 + c8]);
        acc += w * x; den += w;
    }

    acc += __shfl_xor(acc, 8); acc += __shfl_xor(acc, 16); acc += __shfl_xor(acc, 32);
    den += __shfl_xor(den, 8); den += __shfl_xor(den, 16); den += __shfl_xor(den, 32);

    if (eslot == 0)
        h3[(size_t)node * 64 + col] = acc / (den + 1e-16f);
}

// ---------------------------------------------------------------------------
// final2: bias + log_softmax over 40 classes. Wave per node, lanes 0..39.
// ---------------------------------------------------------------------------
__global__ __launch_bounds__(256) void final2_k(
    const float* __restrict__ h3, const float* __restrict__ b2,
    float* __restrict__ out)
{
    int node = blockIdx.x * 4 + (threadIdx.x >> 6);
    int L = threadIdx.x & 63;
    bool act = L < 40;
    float v = act ? h3[(size_t)node * 64 + L] + b2[L] : -1e30f;
    float mx = v;
#pragma unroll
    for (int off = 32; off; off >>= 1) mx = fmaxf(mx, __shfl_xor(mx, off));
    float ex = act ? __expf(v - mx) : 0.f;
#pragma unroll
    for (int off = 32; off; off >>= 1) ex += __shfl_xor(ex, off);
    if (act) out[(size_t)node * 40 + L] = v - mx - logf(ex);
}

// ---------------------------------------------------------------------------
extern "C" void kernel_launch(void* const* d_in, const int* in_sizes, int n_in,
                              void* d_out, int out_size, void* d_ws, size_t ws_size,
                              hipStream_t stream)
{
    const float* x   = (const float*)d_in[0];
    const int*   ei  = (const int*)d_in[1];
    const float* W1  = (const float*)d_in[2];
    const float* as1 = (const float*)d_in[3];
    const float* ad1 = (const float*)d_in[4];
    const float* b1  = (const float*)d_in[5];
    const float* W2  = (const float*)d_in[6];
    const float* as2 = (const float*)d_in[7];
    const float* ad2 = (const float*)d_in[8];
    const float* b2  = (const float*)d_in[9];
    float* out = (float*)d_out;

    float* ws = (float*)d_ws;
    // workspace layout (4B units); total ~27.1M = 108 MB
    __half* h1p   = (__half*)ws;                  // 8 panels x N*16 halves = 6.4M f32; reused as h2p (8 x N*8)
    __half* out1h = (__half*)(ws + 6400000);      // N*128 halves = 3.2M f32
    float* h3    = ws + 9600000;                  // N*64 fp32
    float* asrc1 = ws + 16000000;                 // 2N
    float* adst1 = ws + 16200000;                 // 2N
    float* asrc2 = ws + 16400000;                 // N
    float* adst2 = ws + 16500000;                 // N
    int* bcur      = (int*)(ws + 16600000);       // NB
    int* bbase     = (int*)(ws + 16601000);       // NB
    int* row_start = (int*)(ws + 16602000);       // N+1
    int* csr_src   = (int*)(ws + 16710000);       // E_TOT + 16 pad
    unsigned* bdata = (unsigned*)(ws + 18500000); // NB*BCAP = 2.1M
    unsigned short* xb  = (unsigned short*)(ws + 20600000);  // N*128 bf16
    unsigned short* W1b = (unsigned short*)(ws + 27000000);  // 16384 bf16

    // zero bucket cursors only (2 KB)
    hipMemsetAsync(bcur, 0, NB * sizeof(int), stream);

    // prep: x -> bf16, W1 -> bf16 fragment order
    xprep_k<<<12500, 256, 0, stream>>>(x, xb);
    w1prep_k<<<1, 256, 0, stream>>>(W1, W1b);

    // CSR build: bin -> scan -> build
    bin_k<<<NBIN_WG, 256, 0, stream>>>(ei, bcur, bdata);
    scanb_k<<<1, 512, 0, stream>>>(bcur, bbase);
    build_k<<<NB, 256, 0, stream>>>(bdata, bcur, bbase, row_start, csr_src);

    // layer 1
    gemm1_k<<<1563, 256, 0, stream>>>(xb, W1b, as1, ad1, h1p, asrc1, adst1);
    fagg1_k<<<200000, 256, 0, stream>>>(csr_src, row_start, asrc1, adst1, h1p, b1, out1h);

    // layer 2 (h2p reuses h1p region)
    __half* h2p = h1p;
    gemm2_k<<<1563, 256, 0, stream>>>(out1h, W2, as2, ad2, h2p, asrc2, adst2);
    fagg2_k<<<200000, 256, 0, stream>>>(csr_src, row_start, asrc2, adst2, h2p, h3);
    final2_k<<<25000, 256, 0, stream>>>(h3, b2, out);
}

// Round 12
// 314.042 us; speedup vs baseline: 2.7271x; 2.7271x over previous
//
#include <hip/hip_runtime.h>
#include <hip/hip_fp16.h>
#include <math.h>

#define N_NODES 100000
#define N_EDGES 1600000
#define E_TOT   (N_EDGES + N_NODES)

// bucketed CSR build
#define NB     512          // buckets
#define NPB    196          // dst-nodes per bucket (512*196 = 100352 >= N)
#define BCAP   4096         // capacity per bucket (mean 3332, +13 sigma)
#define BIN_CH 4096         // edges per bin_k workgroup
#define NBIN_WG ((E_TOT + BIN_CH - 1) / BIN_CH)

typedef __attribute__((ext_vector_type(8))) short short8v;   // 8 bf16
typedef __attribute__((ext_vector_type(4))) float float4v;

__device__ __forceinline__ float wexp(float v) {
    v = v > 0.f ? v : 0.2f * v;
    return __expf(v);
}

__device__ __forceinline__ unsigned short f2bf(float f) {
    unsigned u = __float_as_uint(f);
    return (unsigned short)((u + 0x7FFFu + ((u >> 16) & 1u)) >> 16);
}

// ---------------------------------------------------------------------------
// xprep: x fp32 -> bf16 (row-major). 4 elems/thread.
// ---------------------------------------------------------------------------
__global__ __launch_bounds__(256) void xprep_k(
    const float* __restrict__ x, unsigned short* __restrict__ xb)
{
    int gid = blockIdx.x * 256 + threadIdx.x;     // covers N*128/4 exactly
    float4 v = ((const float4*)x)[gid];
    ushort4 o;
    o.x = f2bf(v.x); o.y = f2bf(v.y); o.z = f2bf(v.z); o.w = f2bf(v.w);
    ((ushort4*)xb)[gid] = o;
}

// ---------------------------------------------------------------------------
// w1prep: W1 -> bf16 fragment order [kstep][colfrag][lane][8].
// ---------------------------------------------------------------------------
__global__ __launch_bounds__(256) void w1prep_k(
    const float* __restrict__ W1, unsigned short* __restrict__ W1b)
{
    for (int idx = threadIdx.x; idx < 16384; idx += 256) {
        int i    = idx & 7;
        int lane = (idx >> 3) & 63;
        int f    = (idx >> 9) & 7;
        int ks   = idx >> 12;
        int k   = ks * 32 + (lane >> 4) * 8 + i;
        int col = f * 16 + (lane & 15);
        W1b[idx] = f2bf(W1[k * 128 + col]);
    }
}

// ---------------------------------------------------------------------------
// GEMM1 (MFMA bf16): h1[N,128] = x @ W1, fp16 out; fused alpha reductions.
// Wave = 16 nodes x 128 cols: 4 K-steps x 8 col-frags of 16x16x32.
// C/D: col=lane&15, row=(lane>>4)*4+reg (m89-verified mapping).
// ---------------------------------------------------------------------------
__global__ __launch_bounds__(256) void gemm1_k(
    const unsigned short* __restrict__ xb, const unsigned short* __restrict__ W1b,
    const float* __restrict__ as1, const float* __restrict__ ad1,
    __half* __restrict__ h1h, float* __restrict__ asrc, float* __restrict__ adst)
{
    const int t = threadIdx.x;
    const int w = t >> 6, L = t & 63;
    const int lr = L & 15;            // A-row / C-col within frag
    const int lg = L >> 4;            // k-group / C row-group
    const int nbase = blockIdx.x * 64 + w * 16;

    float4v acc[8];
#pragma unroll
    for (int f = 0; f < 8; ++f) acc[f] = (float4v)0.f;

    int arow = nbase + lr; if (arow >= N_NODES) arow = N_NODES - 1;
    const unsigned short* xrow = xb + (size_t)arow * 128 + lg * 8;

#pragma unroll
    for (int ks = 0; ks < 4; ++ks) {
        short8v a = *(const short8v*)(xrow + ks * 32);
        const unsigned short* wb = W1b + ((size_t)ks * 8 * 64 + L) * 8;
#pragma unroll
        for (int f = 0; f < 8; ++f) {
            short8v b = *(const short8v*)(wb + (size_t)f * 512);
            acc[f] = __builtin_amdgcn_mfma_f32_16x16x32_bf16(a, b, acc[f], 0, 0, 0);
        }
    }

    float as_v[8], ad_v[8];
#pragma unroll
    for (int f = 0; f < 8; ++f) {
        as_v[f] = as1[f * 16 + lr];
        ad_v[f] = ad1[f * 16 + lr];
    }

#pragma unroll
    for (int r = 0; r < 4; ++r) {
        int node = nbase + lg * 4 + r;
        bool ok = node < N_NODES;
        if (ok) {
#pragma unroll
            for (int f = 0; f < 8; ++f)
                h1h[(size_t)node * 128 + f * 16 + lr] = __float2half_rn(acc[f][r]);
        }
        float ps0 = 0.f, pd0 = 0.f, ps1 = 0.f, pd1 = 0.f;
#pragma unroll
        for (int f = 0; f < 4; ++f) { ps0 += acc[f][r] * as_v[f]; pd0 += acc[f][r] * ad_v[f]; }
#pragma unroll
        for (int f = 4; f < 8; ++f) { ps1 += acc[f][r] * as_v[f]; pd1 += acc[f][r] * ad_v[f]; }
#pragma unroll
        for (int off = 1; off < 16; off <<= 1) {
            ps0 += __shfl_xor(ps0, off); pd0 += __shfl_xor(pd0, off);
            ps1 += __shfl_xor(ps1, off); pd1 += __shfl_xor(pd1, off);
        }
        if (lr == 0 && ok) {
            asrc[node * 2 + 0] = ps0; asrc[node * 2 + 1] = ps1;
            adst[node * 2 + 0] = pd0; adst[node * 2 + 1] = pd1;
        }
    }
}

// ---------------------------------------------------------------------------
// CSR build, phase 1: bin edges by dst bucket. Edges read ONCE into regs.
// ---------------------------------------------------------------------------
__global__ __launch_bounds__(256) void bin_k(
    const int* __restrict__ ei, int* __restrict__ bcur, unsigned* __restrict__ bdata)
{
    __shared__ int hist[NB];
    __shared__ int base[NB];
    const int t = threadIdx.x;
    const int e0 = blockIdx.x * BIN_CH;

    int rs[16], rd[16];
#pragma unroll
    for (int p = 0; p < 16; ++p) {
        int e = e0 + p * 256 + t;
        if (e < E_TOT) {
            if (e < N_EDGES) { rs[p] = ei[e]; rd[p] = ei[N_EDGES + e]; }
            else             { rs[p] = rd[p] = e - N_EDGES; }
        } else rd[p] = -1;
    }

    for (int b = t; b < NB; b += 256) hist[b] = 0;
    __syncthreads();

#pragma unroll
    for (int p = 0; p < 16; ++p)
        if (rd[p] >= 0) atomicAdd(&hist[rd[p] / NPB], 1);
    __syncthreads();

    for (int b = t; b < NB; b += 256) {
        int c = hist[b];
        base[b] = c ? atomicAdd(&bcur[b], c) : 0;
        hist[b] = 0;      // reuse as local cursor
    }
    __syncthreads();

#pragma unroll
    for (int p = 0; p < 16; ++p) {
        if (rd[p] < 0) continue;
        int b  = rd[p] / NPB;
        int dl = rd[p] - b * NPB;
        int pos = base[b] + atomicAdd(&hist[b], 1);
        if (pos < BCAP)
            bdata[(size_t)b * BCAP + pos] = (unsigned)rs[p] | ((unsigned)dl << 17);
    }
}

// ---------------------------------------------------------------------------
// CSR build, phase 2a: exclusive scan of bucket counts (1 wg x 512 threads).
// ---------------------------------------------------------------------------
__global__ __launch_bounds__(512) void scanb_k(
    const int* __restrict__ bcur, int* __restrict__ bbase)
{
    __shared__ int a[NB], b_[NB];
    int t = threadIdx.x;
    int v = bcur[t];
    a[t] = v;
    __syncthreads();
    int* src = a; int* dst = b_;
    for (int off = 1; off < NB; off <<= 1) {
        dst[t] = (t >= off) ? src[t - off] + src[t] : src[t];
        __syncthreads();
        int* tmp = src; src = dst; dst = tmp;
    }
    bbase[t] = src[t] - v;   // exclusive
}

// ---------------------------------------------------------------------------
// CSR build, phase 2b: wg per bucket -> row_start + csr_src (contiguous).
// ---------------------------------------------------------------------------
__global__ __launch_bounds__(256) void build_k(
    const unsigned* __restrict__ bdata, const int* __restrict__ bcur,
    const int* __restrict__ bbase, int* __restrict__ row_start,
    int* __restrict__ csr_src)
{
    __shared__ unsigned rec[BCAP];     // 16 KB
    __shared__ int hist[256];
    __shared__ int excl[NPB];
    __shared__ int lcur[NPB];
    const int t = threadIdx.x;
    const int b = blockIdx.x;
    const int cnt = min(bcur[b], BCAP);
    const int bb = bbase[b];

    hist[t] = 0;
    if (t < NPB) lcur[t] = 0;
    __syncthreads();

    for (int i = t; i < cnt; i += 256) {
        unsigned r = bdata[(size_t)b * BCAP + i];
        rec[i] = r;
        atomicAdd(&hist[r >> 17], 1);
    }
    __syncthreads();

    int v = hist[t];
    __syncthreads();
    for (int off = 1; off < 256; off <<= 1) {
        int y = (t >= off) ? hist[t - off] : 0;
        __syncthreads();
        hist[t] += y;
        __syncthreads();
    }
    if (t < NPB) excl[t] = hist[t] - v;
    __syncthreads();

    int node = b * NPB + t;
    if (t < NPB && node <= N_NODES) row_start[node] = bb + excl[t];

    for (int i = t; i < cnt; i += 256) {
        unsigned r = rec[i];
        int dl = r >> 17;
        int s  = r & 0x1FFFF;
        int slot = atomicAdd(&lcur[dl], 1);
        csr_src[bb + excl[dl] + slot] = s;
    }
}

// ---------------------------------------------------------------------------
// Fused layer-1 aggregation: R7 structure widened to 8 independent gather
// chains (no predication in the main body; scalar tail). fp16 out.
// ---------------------------------------------------------------------------
__global__ __launch_bounds__(256) void fagg1_k(
    const int* __restrict__ csr_src, const int* __restrict__ row_start,
    const float* __restrict__ asrc, const float* __restrict__ adst,
    const __half* __restrict__ h1h, const float* __restrict__ b1,
    __half* __restrict__ out1h)
{
    int node = blockIdx.x * 4 + (threadIdx.x >> 6);
    int L = threadIdx.x & 63;
    int h = L >> 5;
    int b = row_start[node], e = row_start[node + 1];
    const float* as_h = asrc + h;
    float ad = adst[node * 2 + h];
    const __half2* H = (const __half2*)h1h;

    float2 a0 = make_float2(0.f, 0.f), a1 = a0, a2 = a0, a3 = a0;
    float2 a4 = a0, a5 = a0, a6 = a0, a7 = a0;
    float d0 = 0.f, d1 = 0.f, d2 = 0.f, d3 = 0.f;
    float d4 = 0.f, d5 = 0.f, d6 = 0.f, d7 = 0.f;

    int j = b;
    for (; j + 7 < e; j += 8) {
        int s0 = csr_src[j],     s1 = csr_src[j + 1], s2 = csr_src[j + 2], s3 = csr_src[j + 3];
        int s4 = csr_src[j + 4], s5 = csr_src[j + 5], s6 = csr_src[j + 6], s7 = csr_src[j + 7];
        float2 x0 = __half22float2(H[(size_t)s0 * 64 + L]);
        float2 x1 = __half22float2(H[(size_t)s1 * 64 + L]);
        float2 x2 = __half22float2(H[(size_t)s2 * 64 + L]);
        float2 x3 = __half22float2(H[(size_t)s3 * 64 + L]);
        float2 x4 = __half22float2(H[(size_t)s4 * 64 + L]);
        float2 x5 = __half22float2(H[(size_t)s5 * 64 + L]);
        float2 x6 = __half22float2(H[(size_t)s6 * 64 + L]);
        float2 x7 = __half22float2(H[(size_t)s7 * 64 + L]);
        float w0 = wexp(as_h[s0 * 2] + ad);
        float w1 = wexp(as_h[s1 * 2] + ad);
        float w2 = wexp(as_h[s2 * 2] + ad);
        float w3 = wexp(as_h[s3 * 2] + ad);
        float w4 = wexp(as_h[s4 * 2] + ad);
        float w5 = wexp(as_h[s5 * 2] + ad);
        float w6 = wexp(as_h[s6 * 2] + ad);
        float w7 = wexp(as_h[s7 * 2] + ad);
        a0.x += w0 * x0.x; a0.y += w0 * x0.y; d0 += w0;
        a1.x += w1 * x1.x; a1.y += w1 * x1.y; d1 += w1;
        a2.x += w2 * x2.x; a2.y += w2 * x2.y; d2 += w2;
        a3.x += w3 * x3.x; a3.y += w3 * x3.y; d3 += w3;
        a4.x += w4 * x4.x; a4.y += w4 * x4.y; d4 += w4;
        a5.x += w5 * x5.x; a5.y += w5 * x5.y; d5 += w5;
        a6.x += w6 * x6.x; a6.y += w6 * x6.y; d6 += w6;
        a7.x += w7 * x7.x; a7.y += w7 * x7.y; d7 += w7;
    }
    for (; j < e; ++j) {
        int s = csr_src[j];
        float w = wexp(as_h[s * 2] + ad);
        float2 xv = __half22float2(H[(size_t)s * 64 + L]);
        a0.x += w * xv.x; a0.y += w * xv.y; d0 += w;
    }

    float den = ((d0 + d1) + (d2 + d3)) + ((d4 + d5) + (d6 + d7));
    float sx  = ((a0.x + a1.x) + (a2.x + a3.x)) + ((a4.x + a5.x) + (a6.x + a7.x));
    float sy  = ((a0.y + a1.y) + (a2.y + a3.y)) + ((a4.y + a5.y) + (a6.y + a7.y));
    float inv = 1.f / (den + 1e-16f);
    float2 bb = ((const float2*)b1)[L];
    float vx = sx * inv + bb.x;
    float vy = sy * inv + bb.y;
    vx = vx > 0.f ? vx : expm1f(vx);
    vy = vy > 0.f ? vy : expm1f(vy);
    ((__half2*)(out1h + (size_t)node * 128))[L] = __floats2half2_rn(vx, vy);
}

// ---------------------------------------------------------------------------
// GEMM2 (LDS-tiled): h2[N,64pad fp16] = out1[N,128] @ W2[128,40].
// ---------------------------------------------------------------------------
__global__ __launch_bounds__(256) void gemm2_k(
    const __half* __restrict__ in1h, const float* __restrict__ W2,
    const float* __restrict__ as2, const float* __restrict__ ad2,
    __half* __restrict__ h2h, float* __restrict__ asrc, float* __restrict__ adst)
{
    __shared__ float xs[64][65];      // 16.6 KB
    __shared__ float Wsh[64][64];     // 16 KB
    __shared__ float as_s[64], ad_s[64];
    const int t = threadIdx.x;
    const int nbase = blockIdx.x * 64;
    const int c4 = t & 15;
    const int ng = t >> 4;

    if (t < 64) {
        as_s[t] = (t < 40) ? as2[t] : 0.f;
        ad_s[t] = (t < 40) ? ad2[t] : 0.f;
    }

    float acc[4][4];
#pragma unroll
    for (int i = 0; i < 4; ++i)
#pragma unroll
        for (int j = 0; j < 4; ++j) acc[i][j] = 0.f;

    for (int kt = 0; kt < 128; kt += 64) {
        __syncthreads();
        {
            int r = t >> 4;
            int c = (t & 15) * 4;
#pragma unroll
            for (int p = 0; p < 4; ++p) {
                int row = p * 16 + r;
                int gr = nbase + row; if (gr > N_NODES - 1) gr = N_NODES - 1;
                const __half2* src = (const __half2*)(in1h + (size_t)gr * 128 + kt + c);
                float2 f01 = __half22float2(src[0]);
                float2 f23 = __half22float2(src[1]);
                xs[row][c + 0] = f01.x; xs[row][c + 1] = f01.y;
                xs[row][c + 2] = f23.x; xs[row][c + 3] = f23.y;
            }
        }
        for (int i = t; i < 4096; i += 256) {
            int k = i >> 6, c = i & 63;
            Wsh[k][c] = (c < 40) ? W2[(size_t)(kt + k) * 40 + c] : 0.f;
        }
        __syncthreads();

#pragma unroll 4
        for (int k = 0; k < 64; ++k) {
            float4 w = *(const float4*)&Wsh[k][c4 * 4];
            float x0 = xs[ng * 4 + 0][k], x1 = xs[ng * 4 + 1][k];
            float x2 = xs[ng * 4 + 2][k], x3 = xs[ng * 4 + 3][k];
            acc[0][0] += x0 * w.x; acc[0][1] += x0 * w.y; acc[0][2] += x0 * w.z; acc[0][3] += x0 * w.w;
            acc[1][0] += x1 * w.x; acc[1][1] += x1 * w.y; acc[1][2] += x1 * w.z; acc[1][3] += x1 * w.w;
            acc[2][0] += x2 * w.x; acc[2][1] += x2 * w.y; acc[2][2] += x2 * w.z; acc[2][3] += x2 * w.w;
            acc[3][0] += x3 * w.x; acc[3][1] += x3 * w.y; acc[3][2] += x3 * w.z; acc[3][3] += x3 * w.w;
        }
    }

    float4 as4 = *(const float4*)&as_s[c4 * 4];
    float4 ad4 = *(const float4*)&ad_s[c4 * 4];
#pragma unroll
    for (int i = 0; i < 4; ++i) {
        int node = nbase + ng * 4 + i;
        float axx = acc[i][0], ayy = acc[i][1], azz = acc[i][2], aww = acc[i][3];
        if (node < N_NODES) {
            __half2* row = (__half2*)(h2h + (size_t)node * 64);
            row[2 * c4]     = __floats2half2_rn(axx, ayy);
            row[2 * c4 + 1] = __floats2half2_rn(azz, aww);
        }
        float ps = axx * as4.x + ayy * as4.y + azz * as4.z + aww * as4.w;
        float pd = axx * ad4.x + ayy * ad4.y + azz * ad4.z + aww * ad4.w;
#pragma unroll
        for (int off = 1; off < 16; off <<= 1) {
            ps += __shfl_xor(ps, off);
            pd += __shfl_xor(pd, off);
        }
        if ((t & 15) == 0 && node < N_NODES) {
            asrc[node] = ps;
            adst[node] = pd;
        }
    }
}

// ---------------------------------------------------------------------------
// Fused layer-2 aggregation + bias + log_softmax: 8 independent chains.
// ---------------------------------------------------------------------------
__global__ __launch_bounds__(256) void fagg2_k(
    const int* __restrict__ csr_src, const int* __restrict__ row_start,
    const float* __restrict__ asrc, const float* __restrict__ adst,
    const __half* __restrict__ h2h, const float* __restrict__ b2,
    float* __restrict__ out)
{
    int node = blockIdx.x * 4 + (threadIdx.x >> 6);
    int L = threadIdx.x & 63;
    bool act = L < 40;
    int col = act ? L : 0;
    int b = row_start[node], e = row_start[node + 1];
    float ad = adst[node];

    float a0 = 0.f, a1 = 0.f, a2 = 0.f, a3 = 0.f;
    float a4 = 0.f, a5 = 0.f, a6 = 0.f, a7 = 0.f;
    float d0 = 0.f, d1 = 0.f, d2 = 0.f, d3 = 0.f;
    float d4 = 0.f, d5 = 0.f, d6 = 0.f, d7 = 0.f;

    int j = b;
    for (; j + 7 < e; j += 8) {
        int s0 = csr_src[j],     s1 = csr_src[j + 1], s2 = csr_src[j + 2], s3 = csr_src[j + 3];
        int s4 = csr_src[j + 4], s5 = csr_src[j + 5], s6 = csr_src[j + 6], s7 = csr_src[j + 7];
        float x0 = __half2float(h2h[(size_t)s0 * 64 + col]);
        float x1 = __half2float(h2h[(size_t)s1 * 64 + col]);
        float x2 = __half2float(h2h[(size_t)s2 * 64 + col]);
        float x3 = __half2float(h2h[(size_t)s3 * 64 + col]);
        float x4 = __half2float(h2h[(size_t)s4 * 64 + col]);
        float x5 = __half2float(h2h[(size_t)s5 * 64 + col]);
        float x6 = __half2float(h2h[(size_t)s6 * 64 + col]);
        float x7 = __half2float(h2h[(size_t)s7 * 64 + col]);
        float w0 = wexp(asrc[s0] + ad);
        float w1 = wexp(asrc[s1] + ad);
        float w2 = wexp(asrc[s2] + ad);
        float w3 = wexp(asrc[s3] + ad);
        float w4 = wexp(asrc[s4] + ad);
        float w5 = wexp(asrc[s5] + ad);
        float w6 = wexp(asrc[s6] + ad);
        float w7 = wexp(asrc[s7] + ad);
        a0 += w0 * x0; d0 += w0;
        a1 += w1 * x1; d1 += w1;
        a2 += w2 * x2; d2 += w2;
        a3 += w3 * x3; d3 += w3;
        a4 += w4 * x4; d4 += w4;
        a5 += w5 * x5; d5 += w5;
        a6 += w6 * x6; d6 += w6;
        a7 += w7 * x7; d7 += w7;
    }
    for (; j < e; ++j) {
        int s = csr_src[j];
        float w = wexp(asrc[s] + ad);
        float xv = __half2float(h2h[(size_t)s * 64 + col]);
        a0 += w * xv; d0 += w;
    }

    float den = ((d0 + d1) + (d2 + d3)) + ((d4 + d5) + (d6 + d7));
    float acc = ((a0 + a1) + (a2 + a3)) + ((a4 + a5) + (a6 + a7));
    float v = act ? acc / (den + 1e-16f) + b2[L] : -1e30f;
    float mx = v;
#pragma unroll
    for (int off = 32; off; off >>= 1) mx = fmaxf(mx, __shfl_xor(mx, off));
    float ex = act ? __expf(v - mx) : 0.f;
#pragma unroll
    for (int off = 32; off; off >>= 1) ex += __shfl_xor(ex, off);
    if (act) out[(size_t)node * 40 + L] = v - mx - logf(ex);
}

// ---------------------------------------------------------------------------
extern "C" void kernel_launch(void* const* d_in, const int* in_sizes, int n_in,
                              void* d_out, int out_size, void* d_ws, size_t ws_size,
                              hipStream_t stream)
{
    const float* x   = (const float*)d_in[0];
    const int*   ei  = (const int*)d_in[1];
    const float* W1  = (const float*)d_in[2];
    const float* as1 = (const float*)d_in[3];
    const float* ad1 = (const float*)d_in[4];
    const float* b1  = (const float*)d_in[5];
    const float* W2  = (const float*)d_in[6];
    const float* as2 = (const float*)d_in[7];
    const float* ad2 = (const float*)d_in[8];
    const float* b2  = (const float*)d_in[9];
    float* out = (float*)d_out;

    float* ws = (float*)d_ws;
    // workspace layout (4B units); total ~27.4M = 109.6 MB
    __half* h1h   = (__half*)ws;                  // N*128 halves; reused as h2h (N*64 halves)
    __half* out1h = (__half*)(ws + 6400000);      // N*128 halves
    float* asrc1 = ws + 19200000;                 // 2N
    float* adst1 = ws + 19400000;                 // 2N
    float* asrc2 = ws + 19600000;                 // N
    float* adst2 = ws + 19700000;                 // N
    int* bcur      = (int*)(ws + 20110000);       // NB
    int* bbase     = (int*)(ws + 20111000);       // NB
    int* row_start = (int*)(ws + 20112000);       // N+1
    int* csr_src   = (int*)(ws + 20220000);       // E_TOT
    unsigned* bdata = (unsigned*)(ws + 22000000); // NB*BCAP = 2.1M
    unsigned short* xb  = (unsigned short*)(ws + 24100000);  // N*128 bf16
    unsigned short* W1b = (unsigned short*)(ws + 27300000);  // 16384 bf16

    // zero bucket cursors only (2 KB)
    hipMemsetAsync(bcur, 0, NB * sizeof(int), stream);

    // prep: x -> bf16, W1 -> bf16 fragment order
    xprep_k<<<12500, 256, 0, stream>>>(x, xb);
    w1prep_k<<<1, 256, 0, stream>>>(W1, W1b);

    // CSR build: bin -> scan -> build
    bin_k<<<NBIN_WG, 256, 0, stream>>>(ei, bcur, bdata);
    scanb_k<<<1, 512, 0, stream>>>(bcur, bbase);
    build_k<<<NB, 256, 0, stream>>>(bdata, bcur, bbase, row_start, csr_src);

    // layer 1
    gemm1_k<<<1563, 256, 0, stream>>>(xb, W1b, as1, ad1, h1h, asrc1, adst1);
    fagg1_k<<<25000, 256, 0, stream>>>(csr_src, row_start, asrc1, adst1, h1h, b1, out1h);

    // layer 2 (h2h reuses h1h region, stride 64 halves = one 128B line)
    __half* h2h = h1h;
    gemm2_k<<<1563, 256, 0, stream>>>(out1h, W2, as2, ad2, h2h, asrc2, adst2);
    fagg2_k<<<25000, 256, 0, stream>>>(csr_src, row_start, asrc2, adst2, h2h, b2, out);
}